// Round 7
// baseline (75.831 us; speedup 1.0000x reference)
//
#include <hip/hip_runtime.h>

// Problem constants (from reference)
#define N_ 16
#define A_ 4096
#define G_ 256
#define C_ 80
#define BIG_ 1e8f
#define LN2_ 0.69314718055994531f

// ROUND 7 = DIAGNOSTIC ABLATION #2 (correctness-preserving).
// Base = round 4 (15.31us). Two repeated phases:
//   - argmin phase x5 (calibrated round 6: +3.83us/extra rep -> 30.63 total)
//   - focal-math phase x17 (register-only; F = (dur - 30.63)/16)
// Also pushes dur past the ~43us fill dispatches so the kernel finally
// appears in the top-5 counter rows (VALUBusy / Occupancy / FETCH readable).
// Identity asm freshens inputs per repeat (defeats CSE) and keeps results
// live (defeats DCE); the last repeat feeds the real epilogue -> output is
// bit-identical to round 4.
#define AREPEAT_ 5
#define FREPEAT_ 17

__global__ __launch_bounds__(256, 4) void cbppl_fused_kernel(
    const float* __restrict__ gt_padded,    // (N, G, 4)
    const float* __restrict__ prop_boxes,   // (N, A, 4)
    const float* __restrict__ pred_boxes,   // (N, A, 4)
    const float* __restrict__ class_logits, // (N, A, C)
    const int*   __restrict__ gt_masks,     // (N, G) bool->int32
    const int*   __restrict__ gt_classes,   // (N, G)
    float* __restrict__ out_cls,            // (N, A)
    float* __restrict__ out_proj)           // (N, A)
{
    __shared__ float4 s_gt[G_];
    __shared__ int    s_cls[G_];

    const int t   = threadIdx.x;
    const int sub = t & 15;                 // lane-in-group
    const int n   = blockIdx.x >> 6;        // 64 blocks per batch
    const int ab  = (blockIdx.x & 63) << 6; // 64 anchors per block

    // ---- one-time: stage masked gt boxes + classes to LDS ----
    {
        const int gidx = n * G_ + t;        // t == g (256 threads)
        float4 g4 = ((const float4*)gt_padded)[gidx];
        if (!gt_masks[gidx]) { g4.x = BIG_; g4.y = BIG_; g4.z = BIG_; g4.w = BIG_; }
        s_gt[t]  = g4;
        s_cls[t] = gt_classes[gidx];
    }
    __syncthreads();

    // ---- one-time: register-cache 16 boxes per lane (interleaved) ----
    float4 b[16];
    #pragma unroll
    for (int m = 0; m < 16; ++m) b[m] = s_gt[sub + (m << 4)];

    // ---- 4 passes: 4 anchors per pass (one per 16-lane group) ----
    #pragma unroll 1
    for (int p = 0; p < 4; ++p) {
        const int ai  = ((t >> 6) << 4) + (p << 2) + ((t >> 4) & 3);
        const int row = n * A_ + ab + ai;

        const float4 pb = ((const float4*)prop_boxes)[row];   // group-broadcast
        const float4 qb = ((const float4*)pred_boxes)[row];

        // 5 logit loads issued early (independent of argmin)
        const float* lrow = class_logits + (size_t)row * C_;
        float xv[5];
        #pragma unroll
        for (int k = 0; k < 5; ++k) xv[k] = lrow[sub + (k << 4)];

        // ======== ABLATION A: argmin phase repeated AREPEAT_ times ========
        float dmin    = 0.0f;
        int   closest = 0;
        #pragma unroll
        for (int rep = 0; rep < AREPEAT_; ++rep) {
            float px = pb.x, py = pb.y, pz = pb.z, pw = pb.w;
            asm volatile("" : "+v"(px), "+v"(py), "+v"(pz), "+v"(pw));

            float dloc = INFINITY;
            int   mloc = 0;
            #pragma unroll
            for (int m = 0; m < 16; ++m) {
                const float d = fabsf(px - b[m].x) + fabsf(py - b[m].y)
                              + fabsf(pz - b[m].z) + fabsf(pw - b[m].w);
                if (d < dloc) { dloc = d; mloc = m; }  // lower m = lower g
            }
            const int iloc = (mloc << 4) + sub;        // g index

            float dm = dloc;
            #pragma unroll
            for (int k = 1; k < 16; k <<= 1) dm = fminf(dm, __shfl_xor(dm, k, 64));
            int cand = (dloc == dm) ? iloc : 0x7FFFFFFF;
            #pragma unroll
            for (int k = 1; k < 16; k <<= 1) cand = min(cand, __shfl_xor(cand, k, 64));

            dmin    = dm;
            closest = cand;
            asm volatile("" :: "v"(dmin), "v"(closest));
        }
        // ==================================================================

        const int nonempty = (dmin < BIG_);

        // epilogue lookups: uniform per group -> LDS broadcast
        const float4 cb     = s_gt[closest];
        const int    target = s_cls[closest];
        const float  pd = fabsf(qb.x - cb.x) + fabsf(qb.y - cb.y)
                        + fabsf(qb.z - cb.z) + fabsf(qb.w - cb.w);

        // dependent broadcast load (once, outside repeats — part of "loads")
        const float xt = lrow[target];

        // ======== ABLATION B: focal math repeated FREPEAT_ times ==========
        float acc = 0.0f;
        #pragma unroll
        for (int rep = 0; rep < FREPEAT_; ++rep) {
            float x0 = xv[0], x1 = xv[1], x2 = xv[2], x3 = xv[3], x4 = xv[4];
            float xtf = xt;
            asm volatile("" : "+v"(x0), "+v"(x1), "+v"(x2),
                              "+v"(x3), "+v"(x4), "+v"(xtf));
            const float xs[5] = {x0, x1, x2, x3, x4};

            float a = 0.0f;
            #pragma unroll
            for (int k = 0; k < 5; ++k) {
                const float x  = xs[k];
                const float e  = __expf(-fabsf(x));
                const float tt = 1.0f + e;
                const float sp = fmaf(LN2_, __log2f(tt), fmaxf(x, 0.0f));
                const float r  = __builtin_amdgcn_rcpf(tt);
                const float pp = (x >= 0.0f) ? r : e * r;
                a += sp * pp * pp;
            }
            a *= 0.75f;

            {
                const float e  = __expf(-fabsf(xtf));
                const float tt = 1.0f + e;
                const float sp = fmaf(LN2_, __log2f(tt), fmaxf(xtf, 0.0f));
                const float r  = __builtin_amdgcn_rcpf(tt);
                const float pp = (xtf >= 0.0f) ? r : e * r;
                const float q  = 1.0f - pp;
                const float corr = 0.25f * (sp - xtf) * q * q - 0.75f * sp * pp * pp;
                a += ((target & 15) == sub) ? corr : 0.0f;
            }

            asm volatile("" :: "v"(a));
            acc = a;
        }
        // ==================================================================

        // group sum of focal partials
        #pragma unroll
        for (int k = 1; k < 16; k <<= 1) acc += __shfl_xor(acc, k, 64);

        if (sub == 0) {
            out_cls[row]  = nonempty ? acc * (1.0f / (float)C_) : 0.0f;
            out_proj[row] = nonempty ? pd : 0.0f;
        }
    }
}

extern "C" void kernel_launch(void* const* d_in, const int* in_sizes, int n_in,
                              void* d_out, int out_size, void* d_ws, size_t ws_size,
                              hipStream_t stream) {
    const float* gt_padded    = (const float*)d_in[0];
    const float* prop_boxes   = (const float*)d_in[1];
    const float* pred_boxes   = (const float*)d_in[2];
    const float* class_logits = (const float*)d_in[3];
    const int*   gt_masks     = (const int*)d_in[4];
    const int*   gt_classes   = (const int*)d_in[5];

    float* out = (float*)d_out;
    float* out_cls  = out;             // classification_loss, (N, A)
    float* out_proj = out + N_ * A_;   // projection_loss,     (N, A)

    dim3 grid(N_ * A_ / 64);           // 1024 blocks, 64 anchors each
    dim3 block(256);
    cbppl_fused_kernel<<<grid, block, 0, stream>>>(
        gt_padded, prop_boxes, pred_boxes, class_logits,
        gt_masks, gt_classes, out_cls, out_proj);
}

// Round 8
// 15.936 us; speedup vs baseline: 4.7585x; 4.7585x over previous
//
#include <hip/hip_runtime.h>

// Problem constants (from reference)
#define N_ 16
#define A_ 4096
#define G_ 256
#define C_ 80
#define BIG_ 1e8f
#define LN2_ 0.69314718055994531f

// Round 8: issue-count attack (round-7 ablation: base is ~70% VALU-busy,
// memory is L2/L3-resident -> instruction-issue-bound).
//  - all per-pass loads hoisted: 1 addr calc + offset-folded dwords per row;
//    p0/p1 issued before LDS staging, p2/p3 after (latency under compute)
//  - no dependent x_target load: owner lane selects from registers
//  - branchless focal: sp = x + ln2*log2(1+e^-x), p = rcp(1+e^-x) (exact)
//  - argmin reduce as ONE u64 key min (4 shuffle stages, exact
//    first-occurrence: keys strictly distinct per lane)
// Masked-out gt boxes staged as (BIG,...): never win; nonempty <=> dmin<BIG.

__device__ __forceinline__ void do_pass(
    const float4 (&b)[16], const float4* s_gt, const int* s_cls,
    const float4 pb, const float4 qb,
    const float x0, const float x1, const float x2, const float x3, const float x4,
    const int sub, const int row,
    float* __restrict__ out_cls, float* __restrict__ out_proj)
{
    // local argmin over this lane's 16 register boxes
    float dloc = INFINITY; int mloc = 0;
    #pragma unroll
    for (int m = 0; m < 16; ++m) {
        const float d = fabsf(pb.x - b[m].x) + fabsf(pb.y - b[m].y)
                      + fabsf(pb.z - b[m].z) + fabsf(pb.w - b[m].w);
        if (d < dloc) { dloc = d; mloc = m; }   // lower m = lower g
    }

    // 16-lane argmin as one u64 min: (bits(d)<<32)|g ; d>=0 so bits monotonic
    unsigned long long key =
        ((unsigned long long)__float_as_uint(dloc) << 32)
        | (unsigned)((mloc << 4) + sub);
    #pragma unroll
    for (int k = 1; k < 16; k <<= 1) {
        const unsigned long long o = __shfl_xor(key, k, 64);
        key = (o < key) ? o : key;
    }
    const int   closest  = (int)(unsigned)key;
    const float dmin     = __uint_as_float((unsigned)(key >> 32));
    const int   nonempty = (dmin < BIG_);

    // group-uniform broadcast lookups
    const float4 cb     = s_gt[closest];
    const int    target = s_cls[closest];
    const float  pd = fabsf(qb.x - cb.x) + fabsf(qb.y - cb.y)
                    + fabsf(qb.z - cb.z) + fabsf(qb.w - cb.w);

    // focal, negative-class closed form (branchless; exact identities):
    //   u = e^-x;  p = 1/(1+u);  softplus = x + ln2*log2(1+u)
    float acc = 0.0f;
    const float xs[5] = {x0, x1, x2, x3, x4};
    #pragma unroll
    for (int j = 0; j < 5; ++j) {
        const float x  = xs[j];
        const float u  = __expf(-x);
        const float tt = 1.0f + u;
        const float sp = fmaf(LN2_, __log2f(tt), x);
        const float r  = __builtin_amdgcn_rcpf(tt);
        acc = fmaf(sp, r * r, acc);
    }
    acc *= 0.75f;

    // target-class correction; xt selected from registers (kt group-uniform)
    {
        const int kt = target >> 4;
        float xt = x0;
        xt = (kt == 1) ? x1 : xt;
        xt = (kt == 2) ? x2 : xt;
        xt = (kt == 3) ? x3 : xt;
        xt = (kt == 4) ? x4 : xt;
        const float u  = __expf(-xt);
        const float tt = 1.0f + u;
        const float sp = fmaf(LN2_, __log2f(tt), xt);
        const float p  = __builtin_amdgcn_rcpf(tt);
        const float q  = 1.0f - p;
        const float corr = fmaf(0.25f * (sp - xt), q * q, -0.75f * sp * p * p);
        acc += ((target & 15) == sub) ? corr : 0.0f;   // only owner lane adds
    }

    // group sum
    #pragma unroll
    for (int k = 1; k < 16; k <<= 1) acc += __shfl_xor(acc, k, 64);

    if (sub == 0) {
        out_cls[row]  = nonempty ? acc * (1.0f / (float)C_) : 0.0f;
        out_proj[row] = nonempty ? pd : 0.0f;
    }
}

__global__ __launch_bounds__(256, 4) void cbppl_fused_kernel(
    const float* __restrict__ gt_padded,    // (N, G, 4)
    const float* __restrict__ prop_boxes,   // (N, A, 4)
    const float* __restrict__ pred_boxes,   // (N, A, 4)
    const float* __restrict__ class_logits, // (N, A, C)
    const int*   __restrict__ gt_masks,     // (N, G) bool->int32
    const int*   __restrict__ gt_classes,   // (N, G)
    float* __restrict__ out_cls,            // (N, A)
    float* __restrict__ out_proj)           // (N, A)
{
    __shared__ float4 s_gt[G_];
    __shared__ int    s_cls[G_];

    const int t   = threadIdx.x;
    const int sub = t & 15;                 // lane-in-group
    const int n   = blockIdx.x >> 6;        // 64 blocks per batch
    const int ab  = (blockIdx.x & 63) << 6; // 64 anchors per block

    // anchor row for pass p: rowb + 4p
    const int grpbase = ((t >> 6) << 4) + ((t >> 4) & 3);
    const int rowb    = n * A_ + ab + grpbase;

    const float4* pbp = (const float4*)prop_boxes;
    const float4* qbp = (const float4*)pred_boxes;

    // ---- hoisted loads for passes 0,1 (before the LDS staging chain) ----
    const float4 pb0 = pbp[rowb + 0], qb0 = qbp[rowb + 0];
    const float4 pb1 = pbp[rowb + 4], qb1 = qbp[rowb + 4];
    const float* l0 = class_logits + (size_t)(rowb + 0) * C_ + sub;
    const float* l1 = class_logits + (size_t)(rowb + 4) * C_ + sub;
    const float a00 = l0[0], a01 = l0[16], a02 = l0[32], a03 = l0[48], a04 = l0[64];
    const float a10 = l1[0], a11 = l1[16], a12 = l1[32], a13 = l1[48], a14 = l1[64];

    // ---- stage masked gt boxes + classes to LDS ----
    {
        const int gidx = n * G_ + t;        // t == g (256 threads)
        float4 g4 = ((const float4*)gt_padded)[gidx];
        if (!gt_masks[gidx]) { g4.x = BIG_; g4.y = BIG_; g4.z = BIG_; g4.w = BIG_; }
        s_gt[t]  = g4;
        s_cls[t] = gt_classes[gidx];
    }
    __syncthreads();

    // ---- register-cache 16 boxes per lane (interleaved g = sub + 16m) ----
    float4 b[16];
    #pragma unroll
    for (int m = 0; m < 16; ++m) b[m] = s_gt[sub + (m << 4)];

    // ---- hoisted loads for passes 2,3 (latency hides under pass 0/1) ----
    const float4 pb2 = pbp[rowb + 8],  qb2 = qbp[rowb + 8];
    const float4 pb3 = pbp[rowb + 12], qb3 = qbp[rowb + 12];
    const float* l2 = class_logits + (size_t)(rowb + 8)  * C_ + sub;
    const float* l3 = class_logits + (size_t)(rowb + 12) * C_ + sub;
    const float a20 = l2[0], a21 = l2[16], a22 = l2[32], a23 = l2[48], a24 = l2[64];
    const float a30 = l3[0], a31 = l3[16], a32 = l3[32], a33 = l3[48], a34 = l3[64];

    do_pass(b, s_gt, s_cls, pb0, qb0, a00, a01, a02, a03, a04, sub, rowb + 0,  out_cls, out_proj);
    do_pass(b, s_gt, s_cls, pb1, qb1, a10, a11, a12, a13, a14, sub, rowb + 4,  out_cls, out_proj);
    do_pass(b, s_gt, s_cls, pb2, qb2, a20, a21, a22, a23, a24, sub, rowb + 8,  out_cls, out_proj);
    do_pass(b, s_gt, s_cls, pb3, qb3, a30, a31, a32, a33, a34, sub, rowb + 12, out_cls, out_proj);
}

extern "C" void kernel_launch(void* const* d_in, const int* in_sizes, int n_in,
                              void* d_out, int out_size, void* d_ws, size_t ws_size,
                              hipStream_t stream) {
    const float* gt_padded    = (const float*)d_in[0];
    const float* prop_boxes   = (const float*)d_in[1];
    const float* pred_boxes   = (const float*)d_in[2];
    const float* class_logits = (const float*)d_in[3];
    const int*   gt_masks     = (const int*)d_in[4];
    const int*   gt_classes   = (const int*)d_in[5];

    float* out = (float*)d_out;
    float* out_cls  = out;             // classification_loss, (N, A)
    float* out_proj = out + N_ * A_;   // projection_loss,     (N, A)

    dim3 grid(N_ * A_ / 64);           // 1024 blocks, 64 anchors each
    dim3 block(256);
    cbppl_fused_kernel<<<grid, block, 0, stream>>>(
        gt_padded, prop_boxes, pred_boxes, class_logits,
        gt_masks, gt_classes, out_cls, out_proj);
}